// Round 1
// baseline (50.094 us; speedup 1.0000x reference)
//
#include <hip/hip_runtime.h>
#include <math.h>

#define NT 512

// Bit permutation of SWAP (verified on basis vectors):
// permuted state s[idx], idx bits b0..b11 (b0 = MSB):
//   s[idx] = psi[b11 b1 b3] * psi[b2 b4 b6] * psi[b5 b7 b9] * psi[b8 b10 b0]
// result[q,w,e,r] = sum_{u,v} F[qw][u,v] * F[er][v,u],  F[ab] = (M_a (x) M_b) S2,
// S2[(i,j),(k,l)] = s[i*512+j*64+k*8+l]  (symmetric under (ij)<->(kl)).

__global__ __launch_bounds__(NT) void qu4_kernel(const float* __restrict__ P,
                                                 float* __restrict__ out,
                                                 float* __restrict__ ws)
{
    const int tid = threadIdx.x;

    __shared__ float  s2[4096];        // 16 KB
    __shared__ float  a1[4096];        // 16 KB  (per-a intermediate)
    __shared__ float  Fbuf[64 * 65];   // 16.6 KB padded for transpose
    __shared__ float  Mf[4][64];
    __shared__ double Dsh[3][64];      // A (then scaled B)
    __shared__ double Xsh[3][64];      // expm accumulator / U
    __shared__ double Mdsh[4][64];
    __shared__ double Edsh[4][8];
    __shared__ float  psiF[8];
    __shared__ int    sExp[3];
    __shared__ float  part[4][2][64];
    __shared__ double redD[4];

    // ---------------- P0: psi, eigen softmax, antisymmetric A ----------------
    if (tid < 8) {
        int c = tid;  // softmax over rows (axis 0) of x[:32].reshape(4,8)
        double x0 = P[5 + 0*8 + c], x1 = P[5 + 1*8 + c];
        double x2 = P[5 + 2*8 + c], x3 = P[5 + 3*8 + c];
        double mx = fmax(fmax(x0, x1), fmax(x2, x3));
        double e0 = exp(x0 - mx), e1 = exp(x1 - mx), e2 = exp(x2 - mx), e3 = exp(x3 - mx);
        double s = e0 + e1 + e2 + e3;
        Edsh[0][c] = e0 / s; Edsh[1][c] = e1 / s; Edsh[2][c] = e2 / s; Edsh[3][c] = e3 / s;
    }
    if (tid == 8) {
        double av[5]; double ss = 0.0;
        for (int i = 0; i < 5; i++) { av[i] = exp((double)P[i]); ss += av[i] * av[i]; }
        double inv = 1.0 / sqrt(ss);
        psiF[0] = (float)(av[0] * inv);
        psiF[1] = 0.f; psiF[2] = 0.f; psiF[3] = 0.f;
        for (int i = 1; i < 5; i++) psiF[3 + i] = (float)(av[i] * inv);
    }
    if (tid >= 64 && tid < 256) {
        int idx = tid - 64; int a = idx >> 6; int e = idx & 63;
        int r = e >> 3, c = e & 7;
        double v = 0.0;
        if (r < c)      v =  (double)P[37 + a*28 + (7*r - (r*(r-1))/2 + c - r - 1)];
        else if (r > c) v = -(double)P[37 + a*28 + (7*c - (c*(c-1))/2 + r - c - 1)];
        Dsh[a][e] = v;
    }
    __syncthreads();

    // ---------------- P1: expm(A) via scaling-and-squaring + Horner Taylor ----
    if (tid < 3) {
        double mx = 0.0;
        for (int r = 0; r < 8; r++) {
            double s = 0.0;
            for (int c = 0; c < 8; c++) s += fabs(Dsh[tid][r*8 + c]);
            mx = fmax(mx, s);
        }
        int sc = 0;
        while (mx > 0.125 && sc < 30) { mx *= 0.5; sc++; }
        sExp[tid] = sc;
    }
    __syncthreads();
    {
        int a = tid >> 6, e = tid & 63, r = e >> 3, c = e & 7;
        bool act = (tid < 192);
        if (act) {
            Dsh[a][e] = ldexp(Dsh[a][e], -sExp[a]);
            Xsh[a][e] = (r == c) ? 1.0 : 0.0;
        }
        __syncthreads();
        for (int k = 12; k >= 1; --k) {   // X = I + (B*X)/k
            double t = 0.0;
            if (act) {
                #pragma unroll
                for (int u = 0; u < 8; u++) t += Dsh[a][r*8 + u] * Xsh[a][u*8 + c];
            }
            __syncthreads();
            if (act) Xsh[a][e] = ((r == c) ? 1.0 : 0.0) + t / (double)k;
            __syncthreads();
        }
        int smax = max(sExp[0], max(sExp[1], sExp[2]));
        for (int tq = 0; tq < smax; tq++) {
            bool act2 = act && (tq < sExp[a]);
            double v = 0.0;
            if (act2) {
                #pragma unroll
                for (int u = 0; u < 8; u++) v += Xsh[a][r*8 + u] * Xsh[a][u*8 + c];
            }
            __syncthreads();
            if (act2) Xsh[a][e] = v;
            __syncthreads();
        }
        // ---------------- P2: M_a = U diag(E_a) U^T ; M3 = I - sum ----------
        if (act) {
            double s = 0.0;
            #pragma unroll
            for (int u = 0; u < 8; u++) s += Xsh[a][r*8 + u] * Edsh[a][u] * Xsh[a][c*8 + u];
            Mdsh[a][e] = s;
        }
        __syncthreads();
        if (tid < 64) {
            int r2 = tid >> 3, c2 = tid & 7;
            Mdsh[3][tid] = ((r2 == c2) ? 1.0 : 0.0) - Mdsh[0][tid] - Mdsh[1][tid] - Mdsh[2][tid];
        }
        __syncthreads();
        if (tid < 256) {
            float mv = (float)Mdsh[tid >> 6][tid & 63];
            Mf[tid >> 6][tid & 63] = mv;
            out[257 + tid] = mv;            // m output  [4,8,8]
        }
    }
    __syncthreads();

    // ---------------- P3: permuted product state s2 --------------------------
    for (int i = tid; i < 4096; i += NT) {
        int b11 = i & 1,        b10 = (i >> 1) & 1, b9 = (i >> 2) & 1, b8 = (i >> 3) & 1;
        int b7  = (i >> 4) & 1, b6  = (i >> 5) & 1, b5 = (i >> 6) & 1, b4 = (i >> 7) & 1;
        int b3  = (i >> 8) & 1, b2  = (i >> 9) & 1, b1 = (i >> 10) & 1, b0 = (i >> 11) & 1;
        float p1 = psiF[(b11 << 2) | (b1 << 1) | b3];
        float p2 = psiF[(b2  << 2) | (b4 << 1) | b6];
        float p3 = psiF[(b5  << 2) | (b7 << 1) | b9];
        float p4 = psiF[(b8  << 2) | (b10 << 1) | b0];
        s2[i] = ((p1 * p2) * p3) * p4;
    }
    __syncthreads();

    float* wsF  = ws;             // 16 x 4096 : F[p][u*64+v]
    float* wsFT = ws + 16 * 4096; // 16 x 4096 : F[p] transposed rows

    // ---------------- P4: build F[p]=(M_a (x) M_b) S2, store F and F^T -------
    for (int a = 0; a < 4; a++) {
        for (int o = tid; o < 4096; o += NT) {        // a1[m][j][kl] = sum_i Ma[m,i] s2[i][j][kl]
            int m = o >> 9, rest = o & 511;
            float s = 0.f;
            #pragma unroll
            for (int i = 0; i < 8; i++) s += Mf[a][(m << 3) + i] * s2[(i << 9) + rest];
            a1[o] = s;
        }
        __syncthreads();
        for (int b = 0; b < 4; b++) {
            int p = a * 4 + b;
            for (int o = tid; o < 4096; o += NT) {    // F[m][n][kl] = sum_j Mb[n,j] a1[m][j][kl]
                int u = o >> 6, m = o >> 9, n = (o >> 6) & 7, kl = o & 63;
                float s = 0.f;
                #pragma unroll
                for (int j = 0; j < 8; j++) s += Mf[b][(n << 3) + j] * a1[(m << 9) + (j << 6) + kl];
                Fbuf[u * 65 + kl] = s;
                wsF[p * 4096 + o] = s;
            }
            __syncthreads();
            for (int o = tid; o < 4096; o += NT)      // coalesced transposed copy
                wsFT[p * 4096 + o] = Fbuf[(o & 63) * 65 + (o >> 6)];
            __syncthreads();
        }
    }

    // ---------------- P5: C[p][q] = dot(F[p], F[q]^T)  (16x16, K=4096) -------
    {
        int tile = tid >> 7;          // 4 tiles of 8x8 outputs
        int ks   = tid & 127;         // K split 128 ways
        int pt = tile >> 1, qt = tile & 1;
        const float* xb = wsF  + (pt * 8) * 4096;
        const float* yb = wsFT + (qt * 8) * 4096;
        float acc[8][8];
        #pragma unroll
        for (int i = 0; i < 8; i++)
            #pragma unroll
            for (int j = 0; j < 8; j++) acc[i][j] = 0.f;
        for (int kk = ks * 4; kk < 4096; kk += 512) {
            float4 xv[8], yv[8];
            #pragma unroll
            for (int i = 0; i < 8; i++) xv[i] = *(const float4*)(xb + i * 4096 + kk);
            #pragma unroll
            for (int j = 0; j < 8; j++) yv[j] = *(const float4*)(yb + j * 4096 + kk);
            #pragma unroll
            for (int i = 0; i < 8; i++)
                #pragma unroll
                for (int j = 0; j < 8; j++)
                    acc[i][j] += xv[i].x * yv[j].x + xv[i].y * yv[j].y
                               + xv[i].z * yv[j].z + xv[i].w * yv[j].w;
        }
        #pragma unroll
        for (int i = 0; i < 8; i++)
            #pragma unroll
            for (int j = 0; j < 8; j++) {
                float v = acc[i][j];
                #pragma unroll
                for (int d = 1; d < 64; d <<= 1) v += __shfl_xor(v, d, 64);
                acc[i][j] = v;
            }
        if ((tid & 63) == 0) {
            int w2 = (tid >> 6) & 1;
            #pragma unroll
            for (int i = 0; i < 8; i++)
                #pragma unroll
                for (int j = 0; j < 8; j++) part[tile][w2][i * 8 + j] = acc[i][j];
        }
    }
    __syncthreads();

    // ---------------- P6: result output + KL divergence ----------------------
    {
        double yterm = 0.0;
        if (tid < 256) {
            int pp = tid >> 4, qq = tid & 15;
            int tile = ((pp >> 3) << 1) | (qq >> 3);
            int loc  = (pp & 7) * 8 + (qq & 7);
            float Cv = part[tile][0][loc] + part[tile][1][loc];
            out[1 + tid] = Cv;                      // result [4,4,4,4]
            int q = (tid >> 6) & 3, w = (tid >> 4) & 3, e = (tid >> 2) & 3, r = tid & 3;
            const float OA = 0.9f / 256.f;          // (1-V)/2^8,    V = 0.1
            const float OB = 3.5f / 768.f;          // (3+5V)/(2^8*3)
            const float OC = 4.3f / 768.f;          // (3+13V)/(2^8*3)
            float obj;
            if (q != w && w != e && e != r && q != r) {
                if (q == e || w == r) obj = (q == e && w == r) ? OA : OB;
                else                  obj = OC;
            } else obj = OA;
            yterm = (double)obj * log((double)obj / (double)Cv);
            #pragma unroll
            for (int d = 1; d < 64; d <<= 1) yterm += __shfl_xor(yterm, d, 64);
            if ((tid & 63) == 0) redD[tid >> 6] = yterm;
        }
        __syncthreads();
        if (tid == 0) out[0] = (float)(redD[0] + redD[1] + redD[2] + redD[3]);
    }
}

extern "C" void kernel_launch(void* const* d_in, const int* in_sizes, int n_in,
                              void* d_out, int out_size, void* d_ws, size_t ws_size,
                              hipStream_t stream)
{
    const float* P = (const float*)d_in[0];
    float* out = (float*)d_out;
    float* ws  = (float*)d_ws;   // needs 16*4096*2 floats = 512 KB
    qu4_kernel<<<1, NT, 0, stream>>>(P, out, ws);
}

// Round 2
// 20.369 us; speedup vs baseline: 2.4593x; 2.4593x over previous
//
#include <hip/hip_runtime.h>
#include <math.h>

// Qu4: params[121] -> y (KL), result[4,4,4,4], m[4,8,8]
//
// SWAP is a pure bit permutation (verified R0): permuted state
//   s[idx], idx bits b0..b11 (b0=MSB):
//   s[idx] = psi[b11 b1 b3] * psi[b2 b4 b6] * psi[b5 b7 b9] * psi[b8 b10 b0]
// With S2 = 64x64 reshape of s (symmetric under leg-pair swap):
//   result[(ab),(cd)] = C[p][q] = sum_{u,v} F_p[u,v] F_q[v,u],
//   F_p = (M_a (x) M_b) S2.
//
// K1 (1 block): psi, softmax E, per-wave shuffle-based f32 expm (no barriers
//               in the loop), M = U diag(e) U^T, M3 = I - sum, s2 -> ws.
// K2 (256 blocks, one per (p,q)): build F_p, F_q^T in LDS from s2, dot,
//               write result, atomicAdd KL term into out[0].
//
// ws layout: [0..4095] s2, [4096..4351] M (4x64).

__global__ __launch_bounds__(256) void qu4_k1(const float* __restrict__ P,
                                              float* __restrict__ out,
                                              float* __restrict__ ws)
{
    const int tid  = threadIdx.x;
    const int wave = tid >> 6;
    const int lane = tid & 63;

    __shared__ float Esh[4][8];
    __shared__ float psiF[8];
    __shared__ float Mf[4][64];

    float X = 0.f;                 // expm result, lives in waves 0..2
    const int r = lane >> 3, c = lane & 7;

    if (wave == 3) {
        if (lane < 8) {            // softmax over axis 0 of x[:32].reshape(4,8)
            float x0 = P[5 + 0*8 + lane], x1 = P[5 + 1*8 + lane];
            float x2 = P[5 + 2*8 + lane], x3 = P[5 + 3*8 + lane];
            float mx = fmaxf(fmaxf(x0, x1), fmaxf(x2, x3));
            float e0 = expf(x0 - mx), e1 = expf(x1 - mx);
            float e2 = expf(x2 - mx), e3 = expf(x3 - mx);
            float s = e0 + e1 + e2 + e3;
            Esh[0][lane] = e0 / s; Esh[1][lane] = e1 / s;
            Esh[2][lane] = e2 / s; Esh[3][lane] = e3 / s;
        } else if (lane == 8) {    // psi
            float av[5]; float ss = 0.f;
            for (int i = 0; i < 5; i++) { av[i] = expf(P[i]); ss += av[i] * av[i]; }
            float inv = 1.f / sqrtf(ss);
            psiF[0] = av[0] * inv;
            psiF[1] = 0.f; psiF[2] = 0.f; psiF[3] = 0.f;
            for (int i = 1; i < 5; i++) psiF[3 + i] = av[i] * inv;
        } else if (lane == 9) {
            out[0] = 0.f;          // KL accumulator (K2 atomicAdds into it)
        }
    } else {
        // ---- antisymmetric generator for matrix `wave`, one element/lane ----
        float B;
        if (r < c)      B =  P[37 + wave*28 + (7*r - (r*(r-1))/2 + c - r - 1)];
        else if (r > c) B = -P[37 + wave*28 + (7*c - (c*(c-1))/2 + r - c - 1)];
        else            B = 0.f;
        // inf-norm via butterfly: row sums then max over rows
        float s = fabsf(B);
        s += __shfl_xor(s, 1, 64); s += __shfl_xor(s, 2, 64); s += __shfl_xor(s, 4, 64);
        float mx = s;
        mx = fmaxf(mx, __shfl_xor(mx, 8, 64));
        mx = fmaxf(mx, __shfl_xor(mx, 16, 64));
        mx = fmaxf(mx, __shfl_xor(mx, 32, 64));
        int sc = 0;
        while (mx > 0.125f && sc < 30) { mx *= 0.5f; sc++; }
        B = ldexpf(B, -sc);
        // Taylor-12 Horner: X = I + B*X/k, k = 12..1   (no barriers, shuffles only)
        X = (r == c) ? 1.f : 0.f;
        for (int k = 12; k >= 1; --k) {
            float t = 0.f;
            #pragma unroll
            for (int u = 0; u < 8; u++)
                t += __shfl(B, (r << 3) + u, 64) * __shfl(X, (u << 3) + c, 64);
            X = ((r == c) ? 1.f : 0.f) + t / (float)k;
        }
        for (int i = 0; i < sc; i++) {        // squarings (uniform per wave)
            float t = 0.f;
            #pragma unroll
            for (int u = 0; u < 8; u++)
                t += __shfl(X, (r << 3) + u, 64) * __shfl(X, (u << 3) + c, 64);
            X = t;
        }
    }
    __syncthreads();

    // ---- M_a = U diag(E_a) U^T ----
    if (wave < 3) {
        float m = 0.f;
        #pragma unroll
        for (int u = 0; u < 8; u++)
            m += __shfl(X, (r << 3) + u, 64) * Esh[wave][u] * __shfl(X, (c << 3) + u, 64);
        Mf[wave][lane] = m;
    }
    __syncthreads();
    if (tid < 64)
        Mf[3][tid] = (((tid >> 3) == (tid & 7)) ? 1.f : 0.f)
                   - Mf[0][tid] - Mf[1][tid] - Mf[2][tid];
    __syncthreads();

    {   // M -> out + ws
        float mv = Mf[tid >> 6][tid & 63];
        out[257 + tid] = mv;
        ws[4096 + tid] = mv;
    }

    // ---- permuted product state s2 -> ws ----
    for (int i = tid; i < 4096; i += 256) {
        int b11 = i & 1,        b10 = (i >> 1) & 1, b9 = (i >> 2) & 1, b8 = (i >> 3) & 1;
        int b7  = (i >> 4) & 1, b6  = (i >> 5) & 1, b5 = (i >> 6) & 1, b4 = (i >> 7) & 1;
        int b3  = (i >> 8) & 1, b2  = (i >> 9) & 1, b1 = (i >> 10) & 1, b0 = (i >> 11) & 1;
        (void)b4;
        float p1 = psiF[(b11 << 2) | (b1 << 1) | b3];
        float p2 = psiF[(b2  << 2) | (b4 << 1) | b6];
        float p3 = psiF[(b5  << 2) | (b7 << 1) | b9];
        float p4 = psiF[(b8  << 2) | (b10 << 1) | b0];
        ws[i] = ((p1 * p2) * p3) * p4;
    }
}

__global__ __launch_bounds__(512) void qu4_k2(const float* __restrict__ ws,
                                              float* __restrict__ out)
{
    const int tid = threadIdx.x;
    const int bid = blockIdx.x;          // bid = p*16 + q
    const int p = bid >> 4, qq = bid & 15;
    const int a = p >> 2,  b = p & 3;
    const int c = qq >> 2, d = qq & 3;

    __shared__ float s2[4096];
    __shared__ float a1[4096];
    __shared__ float Fp[4096];
    __shared__ float FqT[64 * 65];
    __shared__ float Msh[256];
    __shared__ float partial[8];

    // load s2 (float4, coalesced) + M
    {
        const float4* w4 = (const float4*)ws;
        float4* s24 = (float4*)s2;
        for (int o = tid; o < 1024; o += 512) s24[o] = w4[o];
        if (tid < 256) Msh[tid] = ws[4096 + tid];
    }
    __syncthreads();

    // a1[m,j,kl] = sum_i Ma[m,i] s2[i,j,kl]
    for (int o = tid; o < 4096; o += 512) {
        int m = o >> 9, rest = o & 511;
        float s = 0.f;
        #pragma unroll
        for (int i = 0; i < 8; i++) s += Msh[a*64 + (m << 3) + i] * s2[(i << 9) + rest];
        a1[o] = s;
    }
    __syncthreads();

    // Fp[u=(m,n), v=kl] = sum_j Mb[n,j] a1[m,j,kl]
    for (int o = tid; o < 4096; o += 512) {
        int m = o >> 9, n = (o >> 6) & 7, kl = o & 63;
        float s = 0.f;
        #pragma unroll
        for (int j = 0; j < 8; j++) s += Msh[b*64 + (n << 3) + j] * a1[(m << 9) + (j << 6) + kl];
        Fp[o] = s;
    }
    __syncthreads();

    if (c != a) {   // rebuild a1 with Mc (block-uniform branch)
        for (int o = tid; o < 4096; o += 512) {
            int m = o >> 9, rest = o & 511;
            float s = 0.f;
            #pragma unroll
            for (int i = 0; i < 8; i++) s += Msh[c*64 + (m << 3) + i] * s2[(i << 9) + rest];
            a1[o] = s;
        }
        __syncthreads();
    }

    // Fq, stored transposed with +1 pad: FqT[v*65+u] = Fq[u,v]  (bank-clean)
    for (int o = tid; o < 4096; o += 512) {
        int m = o >> 9, n = (o >> 6) & 7, kl = o & 63;
        float s = 0.f;
        #pragma unroll
        for (int j = 0; j < 8; j++) s += Msh[d*64 + (n << 3) + j] * a1[(m << 9) + (j << 6) + kl];
        int u = o >> 6, v = o & 63;
        FqT[v * 65 + u] = s;
    }
    __syncthreads();

    // C[p][q] = sum_{u,v} Fp[u,v] * Fq[v,u] = sum_o Fp[o] * FqT[(o>>6)*65 + (o&63)]
    float acc = 0.f;
    for (int o = tid; o < 4096; o += 512)
        acc += Fp[o] * FqT[(o >> 6) * 65 + (o & 63)];
    #pragma unroll
    for (int dd = 1; dd < 64; dd <<= 1) acc += __shfl_xor(acc, dd, 64);
    if ((tid & 63) == 0) partial[tid >> 6] = acc;
    __syncthreads();

    if (tid == 0) {
        float Cv = 0.f;
        #pragma unroll
        for (int i = 0; i < 8; i++) Cv += partial[i];
        out[1 + bid] = Cv;                       // result [4,4,4,4] flat

        // KL term: obj * log(obj / Cv), accumulate into out[0]
        int q = p >> 2, w = p & 3, e = qq >> 2, r = qq & 3;
        const float OA = 0.9f / 256.f;           // (1-V)/2^8,  V = 0.1
        const float OB = 3.5f / 768.f;           // (3+5V)/(2^8*3)
        const float OC = 4.3f / 768.f;           // (3+13V)/(2^8*3)
        float obj;
        if (q != w && w != e && e != r && q != r) {
            if (q == e || w == r) obj = (q == e && w == r) ? OA : OB;
            else                  obj = OC;
        } else obj = OA;
        double term = (double)obj * log((double)obj / (double)Cv);
        atomicAdd(out, (float)term);
    }
}

extern "C" void kernel_launch(void* const* d_in, const int* in_sizes, int n_in,
                              void* d_out, int out_size, void* d_ws, size_t ws_size,
                              hipStream_t stream)
{
    const float* P = (const float*)d_in[0];
    float* out = (float*)d_out;
    float* ws  = (float*)d_ws;   // needs (4096+256)*4 = 17.4 KB
    qu4_k1<<<1, 256, 0, stream>>>(P, out, ws);
    qu4_k2<<<256, 512, 0, stream>>>(ws, out);
}

// Round 3
// 15.368 us; speedup vs baseline: 3.2596x; 1.3254x over previous
//
#include <hip/hip_runtime.h>
#include <math.h>

#define NT 512

// Qu4: params[121] -> y (KL), result[4,4,4,4], m[4,8,8]   --- single block.
//
// Permuted state (SWAP = bit permutation, verified R0):
//   s[idx], idx bits b0..b11 (b0 = MSB):
//   s[idx] = psi[b11 b1 b3] psi[b2 b4 b6] psi[b5 b7 b9] psi[b8 b10 b0]
// W[beta, alpha] = s[beta*64+alpha], beta=(b0..b5), alpha=(b6..b11).
// Rank-16 factorization W = L V^T, bond t=(c1,c2,r3,r4):
//   L[beta,t] = [b5==r3][b0==r4] psi[c1*4+b1*2+b3] psi[b2*4+b4*2+c2]
//   V[alpha,t]= [b11==c1][b6==c2] psi[r3*4+b7*2+b9] psi[b8*4+b10*2+r4]
// G_p = (M_a (x) M_b) L (64x16),  H_p = V^T G_p (16x16),
//   C[p][q] = tr(F_p F_q) = tr(H_p H_q);  result flat = C[p*16+q].

__global__ __launch_bounds__(NT) void qu4_all(const float* __restrict__ P,
                                              float* __restrict__ out)
{
    const int tid  = threadIdx.x;
    const int wave = tid >> 6;
    const int lane = tid & 63;

    __shared__ __align__(16) float Gsh[16384];   // 64 KB : G[p][alpha][t]
    __shared__ __align__(16) float THsh[4096];   // 16 KB : T[a][(mj)][t] -> H[p][t][t']
    __shared__ __align__(16) float LHsh[4160];   // L[beta][t] (0..1023) -> HT padded q*260
    __shared__ float Mf[4 * 64];
    __shared__ float MfT[4 * 64];                // MfT[b][j*8+n] = M_b[n,j]
    __shared__ float Vcsh[64];                   // Vc[h][rr], h=(b7b8b9b10), rr=(r3,r4)
    __shared__ float Esh[4][8];
    __shared__ float psiF[8];
    __shared__ float Csh[256];
    __shared__ double redD[4];

    // ---------------- S0: psi, softmax E, expm (waves 0-2, shuffle-only) -----
    float X = 0.f;
    const int r = lane >> 3, c = lane & 7;

    if (wave == 3) {
        if (lane < 8) {
            float x0 = P[5 + 0*8 + lane], x1 = P[5 + 1*8 + lane];
            float x2 = P[5 + 2*8 + lane], x3 = P[5 + 3*8 + lane];
            float mx = fmaxf(fmaxf(x0, x1), fmaxf(x2, x3));
            float e0 = expf(x0 - mx), e1 = expf(x1 - mx);
            float e2 = expf(x2 - mx), e3 = expf(x3 - mx);
            float s = e0 + e1 + e2 + e3;
            Esh[0][lane] = e0 / s; Esh[1][lane] = e1 / s;
            Esh[2][lane] = e2 / s; Esh[3][lane] = e3 / s;
        } else if (lane == 8) {
            float av[5]; float ss = 0.f;
            for (int i = 0; i < 5; i++) { av[i] = expf(P[i]); ss += av[i] * av[i]; }
            float inv = 1.f / sqrtf(ss);
            psiF[0] = av[0] * inv;
            psiF[1] = 0.f; psiF[2] = 0.f; psiF[3] = 0.f;
            for (int i = 1; i < 5; i++) psiF[3 + i] = av[i] * inv;
        }
    } else if (wave < 3) {
        float B;
        if (r < c)      B =  P[37 + wave*28 + (7*r - (r*(r-1))/2 + c - r - 1)];
        else if (r > c) B = -P[37 + wave*28 + (7*c - (c*(c-1))/2 + r - c - 1)];
        else            B = 0.f;
        float s = fabsf(B);
        s += __shfl_xor(s, 1, 64); s += __shfl_xor(s, 2, 64); s += __shfl_xor(s, 4, 64);
        float mx = s;
        mx = fmaxf(mx, __shfl_xor(mx, 8, 64));
        mx = fmaxf(mx, __shfl_xor(mx, 16, 64));
        mx = fmaxf(mx, __shfl_xor(mx, 32, 64));
        int sc = 0;
        while (mx > 0.125f && sc < 30) { mx *= 0.5f; sc++; }
        B = ldexpf(B, -sc);
        X = (r == c) ? 1.f : 0.f;
        for (int k = 9; k >= 1; --k) {           // X = I + B*X/k
            float t = 0.f;
            #pragma unroll
            for (int u = 0; u < 8; u++)
                t += __shfl(B, (r << 3) + u, 64) * __shfl(X, (u << 3) + c, 64);
            X = ((r == c) ? 1.f : 0.f) + t / (float)k;
        }
        for (int i = 0; i < sc; i++) {           // squarings (wave-uniform count)
            float t = 0.f;
            #pragma unroll
            for (int u = 0; u < 8; u++)
                t += __shfl(X, (r << 3) + u, 64) * __shfl(X, (u << 3) + c, 64);
            X = t;
        }
    }
    __syncthreads();

    // ---------------- S1: M_a = U diag(E_a) U^T ------------------------------
    if (wave < 3) {
        float m = 0.f;
        #pragma unroll
        for (int u = 0; u < 8; u++)
            m += __shfl(X, (r << 3) + u, 64) * Esh[wave][u] * __shfl(X, (c << 3) + u, 64);
        Mf[wave * 64 + lane] = m;
    }
    __syncthreads();

    // ---------------- S2: M3, L, Vc ------------------------------------------
    if (tid < 64)
        Mf[3 * 64 + tid] = (((tid >> 3) == (tid & 7)) ? 1.f : 0.f)
                         - Mf[0*64 + tid] - Mf[1*64 + tid] - Mf[2*64 + tid];
    if (tid >= 64 && tid < 128) {                // Vc[h*4+rr]
        int o = tid - 64, h = o >> 2, rr = o & 3;
        int r3 = rr >> 1, r4 = rr & 1;
        int b7 = (h >> 3) & 1, b8 = (h >> 2) & 1, b9 = (h >> 1) & 1, b10 = h & 1;
        Vcsh[o] = psiF[r3*4 + b7*2 + b9] * psiF[b8*4 + b10*2 + r4];
    }
    for (int o = tid; o < 1024; o += NT) {       // L[beta*16 + t]
        int beta = o >> 4, t = o & 15;
        int c1 = (t >> 3) & 1, c2 = (t >> 2) & 1, r3 = (t >> 1) & 1, r4 = t & 1;
        int b0 = (beta >> 5) & 1, b1 = (beta >> 4) & 1, b2 = (beta >> 3) & 1;
        int b3 = (beta >> 2) & 1, b4 = (beta >> 1) & 1, b5 = beta & 1;
        float v = 0.f;
        if (b5 == r3 && b0 == r4)
            v = psiF[c1*4 + b1*2 + b3] * psiF[b2*4 + b4*2 + c2];
        LHsh[o] = v;
    }
    __syncthreads();

    // ---------------- S3: MfT, m-out, T_a = (M_a (x) I) L --------------------
    if (tid < 256) {
        int b = tid >> 6, x = tid & 63, j = x >> 3, n = x & 7;
        MfT[b * 64 + x] = Mf[b * 64 + n * 8 + j];
        out[257 + tid] = Mf[tid];                // m output [4,8,8]
    }
    for (int o = tid; o < 4096; o += NT) {       // T[a][(m j)][t]
        int a = o >> 10, mj = (o >> 4) & 63, t = o & 15;
        int m = mj >> 3, j = mj & 7;
        float s = 0.f;
        #pragma unroll
        for (int i = 0; i < 8; i++)
            s += Mf[a * 64 + (m << 3) + i] * LHsh[(((i << 3) | j) << 4) | t];
        THsh[o] = s;
    }
    __syncthreads();

    // ---------------- S4: G_p = (I (x) M_b) T_a  (all 16 p) ------------------
    {
        int ab = tid >> 5, m = (tid >> 2) & 7, tq = tid & 3;   // 512 = 16*8*4
        int a = ab >> 2, b = ab & 3;
        float4 acc[8];
        #pragma unroll
        for (int n = 0; n < 8; n++) acc[n] = make_float4(0.f, 0.f, 0.f, 0.f);
        #pragma unroll
        for (int j = 0; j < 8; j++) {
            float4 tv  = *(const float4*)&THsh[a * 1024 + ((m * 8 + j) << 4) + tq * 4];
            float4 mb0 = *(const float4*)&MfT[b * 64 + j * 8];
            float4 mb1 = *(const float4*)&MfT[b * 64 + j * 8 + 4];
            float mbv[8] = {mb0.x, mb0.y, mb0.z, mb0.w, mb1.x, mb1.y, mb1.z, mb1.w};
            #pragma unroll
            for (int n = 0; n < 8; n++) {
                acc[n].x += mbv[n] * tv.x; acc[n].y += mbv[n] * tv.y;
                acc[n].z += mbv[n] * tv.z; acc[n].w += mbv[n] * tv.w;
            }
        }
        #pragma unroll
        for (int n = 0; n < 8; n++)
            *(float4*)&Gsh[ab * 1024 + ((m * 8 + n) << 4) + tq * 4] = acc[n];
    }
    __syncthreads();

    // ---------------- S5: H_p[t][t'] = sum_alpha V[alpha,t] G_p[alpha,t'] ----
    if (tid < 256) {                             // (p, c1, c2, t'-quad)
        int p = tid >> 4, c1 = (tid >> 3) & 1, c2 = (tid >> 2) & 1, tpq = tid & 3;
        float4 hacc[4];
        #pragma unroll
        for (int rr = 0; rr < 4; rr++) hacc[rr] = make_float4(0.f, 0.f, 0.f, 0.f);
        #pragma unroll
        for (int h = 0; h < 16; h++) {
            int alpha = c2 * 32 + h * 2 + c1;
            float4 gv = *(const float4*)&Gsh[p * 1024 + alpha * 16 + tpq * 4];
            float4 vv = *(const float4*)&Vcsh[h * 4];
            hacc[0].x += vv.x * gv.x; hacc[0].y += vv.x * gv.y; hacc[0].z += vv.x * gv.z; hacc[0].w += vv.x * gv.w;
            hacc[1].x += vv.y * gv.x; hacc[1].y += vv.y * gv.y; hacc[1].z += vv.y * gv.z; hacc[1].w += vv.y * gv.w;
            hacc[2].x += vv.z * gv.x; hacc[2].y += vv.z * gv.y; hacc[2].z += vv.z * gv.z; hacc[2].w += vv.z * gv.w;
            hacc[3].x += vv.w * gv.x; hacc[3].y += vv.w * gv.y; hacc[3].z += vv.w * gv.z; hacc[3].w += vv.w * gv.w;
        }
        #pragma unroll
        for (int rr = 0; rr < 4; rr++) {
            int t = (c1 << 3) | (c2 << 2) | rr;
            *(float4*)&THsh[p * 256 + t * 16 + tpq * 4] = hacc[rr];   // H overwrites T
        }
    }
    __syncthreads();

    // ---------------- S6: HT[q][t][t'] = H[q][t'][t]  (padded stride 260) ----
    for (int o = tid; o < 4096; o += NT) {
        int q = o >> 8, tp = (o >> 4) & 15, t = o & 15;
        LHsh[q * 260 + tp * 16 + t] = THsh[q * 256 + t * 16 + tp];
    }
    __syncthreads();

    // ---------------- S7: C[p][q] = <H_p, HT_q>  (flat 256-dot, k-split 2) ---
    {
        int pq = tid >> 1, half = tid & 1;
        int p = pq >> 4, q = pq & 15;
        const float4* Ap = (const float4*)&THsh[p * 256];
        const float4* Bq = (const float4*)&LHsh[q * 260];
        float acc = 0.f;
        #pragma unroll
        for (int k = 0; k < 32; k++) {
            float4 x = Ap[half * 32 + k], y = Bq[half * 32 + k];
            acc += x.x * y.x + x.y * y.y + x.z * y.z + x.w * y.w;
        }
        acc += __shfl_xor(acc, 1, 64);
        if (half == 0) Csh[pq] = acc;
    }
    __syncthreads();

    // ---------------- S8: result out + KL ------------------------------------
    {
        double yterm = 0.0;
        if (tid < 256) {
            float Cv = Csh[tid];
            out[1 + tid] = Cv;
            int q = (tid >> 6) & 3, w = (tid >> 4) & 3, e = (tid >> 2) & 3, rr = tid & 3;
            const float OA = 0.9f / 256.f;       // (1-V)/2^8,  V = 0.1
            const float OB = 3.5f / 768.f;       // (3+5V)/(2^8*3)
            const float OC = 4.3f / 768.f;       // (3+13V)/(2^8*3)
            float obj;
            if (q != w && w != e && e != rr && q != rr) {
                if (q == e || w == rr) obj = (q == e && w == rr) ? OA : OB;
                else                   obj = OC;
            } else obj = OA;
            yterm = (double)obj * log((double)obj / (double)Cv);
            #pragma unroll
            for (int d = 1; d < 64; d <<= 1) yterm += __shfl_xor(yterm, d, 64);
            if ((tid & 63) == 0) redD[tid >> 6] = yterm;
        }
        __syncthreads();
        if (tid == 0) out[0] = (float)(redD[0] + redD[1] + redD[2] + redD[3]);
    }
}

extern "C" void kernel_launch(void* const* d_in, const int* in_sizes, int n_in,
                              void* d_out, int out_size, void* d_ws, size_t ws_size,
                              hipStream_t stream)
{
    const float* P = (const float*)d_in[0];
    float* out = (float*)d_out;
    qu4_all<<<1, NT, 0, stream>>>(P, out);
}